// Round 3
// baseline (36.094 us; speedup 1.0000x reference)
//
#include <hip/hip_runtime.h>

// GazeLoss: B=64, C=3, H=W=512, S=32, PAD=0.3, eyes at landmarks [36:42) and [42:48)
// loss = sum over (b,eye,c,sy,sx) of |bilinear(pred-target)| / 393216
// Single fused kernel: one thread per (b,eye,sy,sx), c-loop inside (24 scattered
// loads/thread). Last-arriving block performs the final reduction (device-scope
// atomic counter in d_ws; mod-trick makes the counter self-maintaining across
// replays regardless of d_ws poisoning).

#define IMG_W 512
#define NBATCH 64
#define N_THREADS (NBATCH * 2 * 1024)   // 131072
#define BLOCK 256
#define NBLOCKS (N_THREADS / BLOCK)      // 512
#define INV_COUNT (1.0f / 393216.0f)

__global__ __launch_bounds__(BLOCK) void gaze_fused_kernel(
    const float* __restrict__ pred,
    const float* __restrict__ target,
    const float* __restrict__ lm,        // (64, 68, 2)
    float* __restrict__ partial,         // NBLOCKS floats (in d_ws)
    unsigned int* __restrict__ counter,  // 1 uint (in d_ws, own cache line)
    float* __restrict__ out)
{
    const int tid = blockIdx.x * BLOCK + threadIdx.x;   // 0 .. 131071
    const int s   = tid & 1023;          // sample within patch
    const int eye = (tid >> 10) & 1;     // 0 = left, 1 = right
    const int b   = tid >> 11;           // batch
    const int sy  = s >> 5;
    const int sx  = s & 31;

    // ---- eye bbox from 6 landmarks (L1-cached; all threads of a (b,eye) share) ----
    const float* lmb = lm + ((size_t)b * 68 + 36 + eye * 6) * 2;
    float x_min = 1e30f, x_max = -1e30f, y_min = 1e30f, y_max = -1e30f;
#pragma unroll
    for (int i = 0; i < 6; ++i) {
        float x = lmb[i * 2 + 0];
        float y = lmb[i * 2 + 1];
        x_min = fminf(x_min, x); x_max = fmaxf(x_max, x);
        y_min = fminf(y_min, y); y_max = fmaxf(y_max, y);
    }
    const float w = x_max - x_min, h = y_max - y_min;

    // clip padded bbox to [0, W-1]
    const float bx1 = fminf(fmaxf(x_min - 0.3f * w, 0.0f), 511.0f);
    const float bx2 = fminf(fmaxf(x_max + 0.3f * w, 0.0f), 511.0f);
    const float by1 = fminf(fmaxf(y_min - 0.3f * h, 0.0f), 511.0f);
    const float by2 = fminf(fmaxf(y_max + 0.3f * h, 0.0f), 511.0f);
    const bool degen = (bx2 - bx1 < 1.0f) || (by2 - by1 < 1.0f);

    // normalized [-1,1] coords, lerp along t = s/31 (reference math order)
    const float xn0 = bx1 * (2.0f / 511.0f) - 1.0f;
    const float xn1 = bx2 * (2.0f / 511.0f) - 1.0f;
    const float yn0 = by1 * (2.0f / 511.0f) - 1.0f;
    const float yn1 = by2 * (2.0f / 511.0f) - 1.0f;
    float gx = xn0 + (xn1 - xn0) * ((float)sx * (1.0f / 31.0f));
    float gy = yn0 + (yn1 - yn0) * ((float)sy * (1.0f / 31.0f));
    if (degen) { gx = 0.0f; gy = 0.0f; }

    // back to pixel coords
    const float px = fminf(fmaxf((gx + 1.0f) * 0.5f * 511.0f, 0.0f), 511.0f);
    const float py = fminf(fmaxf((gy + 1.0f) * 0.5f * 511.0f, 0.0f), 511.0f);

    const float x0 = floorf(px), y0 = floorf(py);
    const float wx = px - x0,    wy = py - y0;
    const int x0i = (int)fminf(fmaxf(x0, 0.0f), 511.0f);
    const int x1i = (int)fminf(x0 + 1.0f, 511.0f);
    const int y0i = (int)fminf(fmaxf(y0, 0.0f), 511.0f);
    const int y1i = (int)fminf(y0 + 1.0f, 511.0f);

    const float wa = (1.0f - wx) * (1.0f - wy);
    const float wb = wx * (1.0f - wy);
    const float wc = (1.0f - wx) * wy;
    const float wd = wx * wy;

    const int ia = y0i * IMG_W + x0i;
    const int ib = y0i * IMG_W + x1i;
    const int ic = y1i * IMG_W + x0i;
    const int id = y1i * IMG_W + x1i;

    float acc = 0.0f;
#pragma unroll
    for (int c = 0; c < 3; ++c) {
        const size_t off = (size_t)(b * 3 + c) * (IMG_W * IMG_W);
        const float* pc = pred + off;
        const float* tc = target + off;
        const float da = pc[ia] - tc[ia];
        const float db = pc[ib] - tc[ib];
        const float dc = pc[ic] - tc[ic];
        const float dd = pc[id] - tc[id];
        acc += fabsf(da * wa + db * wb + dc * wc + dd * wd);
    }

    // ---- block reduction: wave64 shuffle, then LDS across 4 waves ----
#pragma unroll
    for (int o = 32; o > 0; o >>= 1) acc += __shfl_down(acc, o, 64);
    __shared__ float smem[BLOCK / 64];
    __shared__ bool is_last;
    const int lane = threadIdx.x & 63;
    const int wid  = threadIdx.x >> 6;
    if (lane == 0) smem[wid] = acc;
    __syncthreads();
    if (threadIdx.x == 0) {
        float bsum = 0.0f;
#pragma unroll
        for (int i = 0; i < BLOCK / 64; ++i) bsum += smem[i];
        partial[blockIdx.x] = bsum;
        __threadfence();   // release: make partial visible device-wide
        const unsigned prev = atomicAdd(counter, 1u);
        // mod-trick: exactly one block per call triggers, regardless of the
        // counter's starting value (poison-proof, no reset needed; NBLOCKS | 2^32)
        is_last = ((prev & (NBLOCKS - 1)) == (NBLOCKS - 1));
    }
    __syncthreads();

    if (is_last) {
        __threadfence();   // acquire side
        float v = 0.0f;
#pragma unroll
        for (int i = threadIdx.x; i < NBLOCKS; i += BLOCK)
            v += __hip_atomic_load(&partial[i], __ATOMIC_RELAXED,
                                   __HIP_MEMORY_SCOPE_AGENT);
#pragma unroll
        for (int o = 32; o > 0; o >>= 1) v += __shfl_down(v, o, 64);
        if (lane == 0) smem[wid] = v;
        __syncthreads();
        if (threadIdx.x == 0) {
            float total = 0.0f;
#pragma unroll
            for (int i = 0; i < BLOCK / 64; ++i) total += smem[i];
            out[0] = total * INV_COUNT;
        }
    }
}

extern "C" void kernel_launch(void* const* d_in, const int* in_sizes, int n_in,
                              void* d_out, int out_size, void* d_ws, size_t ws_size,
                              hipStream_t stream) {
    const float* pred   = (const float*)d_in[0];
    const float* target = (const float*)d_in[1];
    const float* lm     = (const float*)d_in[2];
    float* out = (float*)d_out;

    // d_ws layout: [0..3] atomic counter (own 128-B line), [128..] partials
    unsigned int* counter = (unsigned int*)d_ws;
    float* partial = (float*)((char*)d_ws + 128);

    gaze_fused_kernel<<<NBLOCKS, BLOCK, 0, stream>>>(pred, target, lm,
                                                     partial, counter, out);
}

// Round 4
// 20.565 us; speedup vs baseline: 1.7552x; 1.7552x over previous
//
#include <hip/hip_runtime.h>

// GazeLoss: B=64, C=3, H=W=512, S=32, PAD=0.3, eyes at landmarks [36:42) and [42:48)
// loss = sum over (b,eye,c,sy,sx) of |bilinear(pred-target)| / 393216
// Two kernels (fused last-block variant regressed: per-block threadfence cost).
// Block mapping XCD-swizzled so all 8 blocks of one batch image (both eyes,
// whose padded bboxes overlap heavily) share one XCD L2.

#define IMG_W 512
#define NBATCH 64
#define BLOCK 256
#define NBLOCKS 512                     // 64 b * 2 eyes * 4 quarter-patches
#define INV_COUNT (1.0f / 393216.0f)

__global__ __launch_bounds__(BLOCK) void gaze_patch_kernel(
    const float* __restrict__ pred,
    const float* __restrict__ target,
    const float* __restrict__ lm,      // (64, 68, 2)
    float* __restrict__ partial)       // (NBLOCKS)
{
    // ---- XCD-coherent remap: consecutive blockIdx round-robin XCDs (p%8).
    // Give all 8 blocks of batch image b the same p%8 -> same XCD L2, so the
    // overlapping left/right eye line sets are fetched from HBM once.
    const int p    = blockIdx.x;
    const int xcd  = p & 7;
    const int slot = p >> 3;                 // 0..63
    const int b    = (xcd << 3) | (slot & 7);  // 0..63, 8 blocks each
    const int rem  = slot >> 3;              // 0..7
    const int eye  = rem & 1;
    const int quarter = rem >> 1;            // 0..3 -> sy block of 8 rows
    const int s    = quarter * 256 + threadIdx.x;  // 0..1023 sample in patch
    const int sy   = s >> 5;
    const int sx   = s & 31;

    // ---- eye bbox from 6 landmarks (uniform per block; L1/scalar-cached) ----
    const float* lmb = lm + ((size_t)b * 68 + 36 + eye * 6) * 2;
    float x_min = 1e30f, x_max = -1e30f, y_min = 1e30f, y_max = -1e30f;
#pragma unroll
    for (int i = 0; i < 6; ++i) {
        float x = lmb[i * 2 + 0];
        float y = lmb[i * 2 + 1];
        x_min = fminf(x_min, x); x_max = fmaxf(x_max, x);
        y_min = fminf(y_min, y); y_max = fmaxf(y_max, y);
    }
    const float w = x_max - x_min, h = y_max - y_min;

    // clip padded bbox to [0, W-1]
    const float bx1 = fminf(fmaxf(x_min - 0.3f * w, 0.0f), 511.0f);
    const float bx2 = fminf(fmaxf(x_max + 0.3f * w, 0.0f), 511.0f);
    const float by1 = fminf(fmaxf(y_min - 0.3f * h, 0.0f), 511.0f);
    const float by2 = fminf(fmaxf(y_max + 0.3f * h, 0.0f), 511.0f);
    const bool degen = (bx2 - bx1 < 1.0f) || (by2 - by1 < 1.0f);

    // normalized [-1,1] coords, lerp along t = s/31 (reference math order)
    const float xn0 = bx1 * (2.0f / 511.0f) - 1.0f;
    const float xn1 = bx2 * (2.0f / 511.0f) - 1.0f;
    const float yn0 = by1 * (2.0f / 511.0f) - 1.0f;
    const float yn1 = by2 * (2.0f / 511.0f) - 1.0f;
    float gx = xn0 + (xn1 - xn0) * ((float)sx * (1.0f / 31.0f));
    float gy = yn0 + (yn1 - yn0) * ((float)sy * (1.0f / 31.0f));
    if (degen) { gx = 0.0f; gy = 0.0f; }

    // back to pixel coords
    const float px = fminf(fmaxf((gx + 1.0f) * 0.5f * 511.0f, 0.0f), 511.0f);
    const float py = fminf(fmaxf((gy + 1.0f) * 0.5f * 511.0f, 0.0f), 511.0f);

    const float x0 = floorf(px), y0 = floorf(py);
    const float wx = px - x0,    wy = py - y0;
    const int x0i = (int)fminf(fmaxf(x0, 0.0f), 511.0f);
    const int x1i = (int)fminf(x0 + 1.0f, 511.0f);
    const int y0i = (int)fminf(fmaxf(y0, 0.0f), 511.0f);
    const int y1i = (int)fminf(y0 + 1.0f, 511.0f);

    const float wa = (1.0f - wx) * (1.0f - wy);
    const float wb = wx * (1.0f - wy);
    const float wc = (1.0f - wx) * wy;
    const float wd = wx * wy;

    const int ia = y0i * IMG_W + x0i;
    const int ib = y0i * IMG_W + x1i;
    const int ic = y1i * IMG_W + x0i;
    const int id = y1i * IMG_W + x1i;

    float acc = 0.0f;
#pragma unroll
    for (int c = 0; c < 3; ++c) {
        const size_t off = (size_t)(b * 3 + c) * (IMG_W * IMG_W);
        const float* pc = pred + off;
        const float* tc = target + off;
        const float da = pc[ia] - tc[ia];
        const float db = pc[ib] - tc[ib];
        const float dc = pc[ic] - tc[ic];
        const float dd = pc[id] - tc[id];
        acc += fabsf(da * wa + db * wb + dc * wc + dd * wd);
    }

    // ---- block reduction: wave64 shuffle, then LDS across 4 waves ----
#pragma unroll
    for (int o = 32; o > 0; o >>= 1) acc += __shfl_down(acc, o, 64);
    __shared__ float smem[BLOCK / 64];
    const int lane = threadIdx.x & 63;
    const int wid  = threadIdx.x >> 6;
    if (lane == 0) smem[wid] = acc;
    __syncthreads();
    if (threadIdx.x == 0) {
        float bsum = 0.0f;
#pragma unroll
        for (int i = 0; i < BLOCK / 64; ++i) bsum += smem[i];
        partial[blockIdx.x] = bsum;
    }
}

__global__ __launch_bounds__(64) void gaze_finalize_kernel(
    const float* __restrict__ partial, float* __restrict__ out)
{
    float v = 0.0f;
#pragma unroll
    for (int i = threadIdx.x; i < NBLOCKS; i += 64) v += partial[i];
#pragma unroll
    for (int o = 32; o > 0; o >>= 1) v += __shfl_down(v, o, 64);
    if (threadIdx.x == 0) out[0] = v * INV_COUNT;
}

extern "C" void kernel_launch(void* const* d_in, const int* in_sizes, int n_in,
                              void* d_out, int out_size, void* d_ws, size_t ws_size,
                              hipStream_t stream) {
    const float* pred   = (const float*)d_in[0];
    const float* target = (const float*)d_in[1];
    const float* lm     = (const float*)d_in[2];
    float* out = (float*)d_out;
    float* partial = (float*)d_ws;   // NBLOCKS floats, fully overwritten each call

    gaze_patch_kernel<<<NBLOCKS, BLOCK, 0, stream>>>(pred, target, lm, partial);
    gaze_finalize_kernel<<<1, 64, 0, stream>>>(partial, out);
}